// Round 6
// baseline (1380.054 us; speedup 1.0000x reference)
//
#include <hip/hip_runtime.h>
#include <hip/hip_bf16.h>
#include <stdint.h>

typedef __attribute__((ext_vector_type(4))) float f32x4;
typedef __attribute__((ext_vector_type(8))) short s16x8;

#define EPSBN 1e-5f

__device__ __forceinline__ float bf2f(unsigned short u) {
  union { unsigned int i; float f; } w; w.i = ((unsigned int)u) << 16; return w.f;
}
__device__ __forceinline__ unsigned short f2bf(float f) {
  __hip_bfloat16 h = __float2bfloat16(f);   // RNE
  unsigned short u; __builtin_memcpy(&u, &h, 2); return u;
}
__device__ __forceinline__ void gld_lds16(const void* g, void* l) {
  __builtin_amdgcn_global_load_lds(
      (const __attribute__((address_space(1))) void*)(g),
      (__attribute__((address_space(3))) void*)(l), 16, 0, 0);
}

// ---------------- graph prep ----------------
__global__ void k_init_deg(unsigned* deg, int n) {
  int i = blockIdx.x * 256 + threadIdx.x;
  if (i < n) deg[i] = 1u;               // self-loop
}
__global__ void k_count(const int* __restrict__ dst, unsigned* __restrict__ deg, int E) {
  int i = blockIdx.x * 256 + threadIdx.x;
  if (i < E) atomicAdd(&deg[dst[i]], 1u);
}
// fused: dinv + per-block degree sums
__global__ void k_prep2(const unsigned* __restrict__ deg, float* __restrict__ dinv,
                        unsigned* __restrict__ bsum, int n) {
  __shared__ unsigned s[256];
  int t = threadIdx.x, i = blockIdx.x * 256 + t;
  unsigned d = (i < n) ? deg[i] : 0u;
  if (i < n) dinv[i] = rsqrtf((float)d);
  s[t] = d;
  __syncthreads();
  for (int st = 128; st > 0; st >>= 1) {
    if (t < st) s[t] += s[t + st];
    __syncthreads();
  }
  if (t == 0) bsum[blockIdx.x] = s[0];
}
__global__ void k_scan_top(const unsigned* __restrict__ bsum, unsigned* __restrict__ bpre,
                           int nb, unsigned* __restrict__ offs, int n) {
  __shared__ unsigned s[256];
  int t = threadIdx.x;
  unsigned v = (t < nb) ? bsum[t] : 0u;
  s[t] = v; __syncthreads();
  for (int d = 1; d < 256; d <<= 1) {
    unsigned a = (t >= d) ? s[t - d] : 0u;
    __syncthreads();
    s[t] += a;
    __syncthreads();
  }
  bpre[t] = s[t] - v;                    // exclusive
  if (t == 255) offs[n] = s[255];        // total = E + n
}
__global__ void k_scan_fin(const unsigned* __restrict__ deg, const unsigned* __restrict__ bpre,
                           unsigned* __restrict__ offs, unsigned* __restrict__ cur, int n) {
  __shared__ unsigned s[256];
  int t = threadIdx.x, i = blockIdx.x * 256 + t;
  unsigned v = (i < n) ? deg[i] : 0u;
  s[t] = v; __syncthreads();
  for (int d = 1; d < 256; d <<= 1) {
    unsigned a = (t >= d) ? s[t - d] : 0u;
    __syncthreads();
    s[t] += a;
    __syncthreads();
  }
  if (i < n) {
    unsigned o = bpre[blockIdx.x] + s[t] - v;
    offs[i] = o; cur[i] = o;
  }
}
// fill CSR directly with packed (src<<16 | bf16(w)); src < 65536 guaranteed (N=50000)
__global__ void k_fillw(const int* __restrict__ src, const int* __restrict__ dst,
                        const float* __restrict__ dinv, unsigned* __restrict__ cur,
                        unsigned* __restrict__ ewp, int E, int n) {
  int i = blockIdx.x * 256 + threadIdx.x;
  int s, d;
  if (i < E)          { s = src[i]; d = dst[i]; }
  else if (i < E + n) { s = d = i - E; }        // self-loop
  else return;
  unsigned p = atomicAdd(&cur[d], 1u);
  float w = dinv[s] * dinv[d];
  ewp[p] = ((unsigned)s << 16) | (unsigned)f2bf(w);
}
// all three weight transposes in one launch. W [K][N] fp32 -> Wt [Npad][K] bf16
__global__ void k_wt3(const float* __restrict__ W1, unsigned short* __restrict__ Wt1,
                      const float* __restrict__ W2, unsigned short* __restrict__ Wt2,
                      const float* __restrict__ W3, unsigned short* __restrict__ Wt3) {
  const int n1 = 256 * 1280, n2 = 256 * 256, n3 = 512 * 256;
  int idx = blockIdx.x * 256 + threadIdx.x;
  const float* W; unsigned short* Wt; int K, N;
  if (idx < n1)            { W = W1; Wt = Wt1; K = 1280; N = 256; }
  else if (idx < n1 + n2)  { W = W2; Wt = Wt2; K = 256;  N = 256; idx -= n1; }
  else if (idx < n1+n2+n3) { W = W3; Wt = Wt3; K = 256;  N = 500; idx -= n1 + n2; }
  else return;
  int nn = idx / K, k = idx - nn * K;
  float v = (nn < N) ? W[(size_t)k * N + nn] : 0.f;
  Wt[idx] = f2bf(v);
}

// ---------------- GEMM (bf16 A): C[M,N] = A[M,K] * Bt[N,K]^T ----------------
// ACM: A stored chunk-major [K/32][M][32]. OUTMODE 0: bf16 chunk-major; 1: f32 row-major + bias.
#define BM 128
#define BN 128
#define BK 64

template<int OUTMODE, int ACM>
__global__ __launch_bounds__(256, 4) void k_gemm(
    const unsigned short* __restrict__ Au, const unsigned short* __restrict__ Bt,
    void* __restrict__ Coutv, const float* __restrict__ bias,
    int M, int N, int K, int MT, int NT)
{
  __shared__ __align__(16) unsigned short As[BM * BK];
  __shared__ __align__(16) unsigned short Bs[BN * BK];

  int d = blockIdx.x;
  int xc = d & 7, sb = d >> 3;
  int nt = sb % NT, mt = (sb / NT) * 8 + xc;
  if (mt >= MT) return;
  int m0 = mt * BM, n0 = nt * BN;

  int tid = threadIdx.x, lane = tid & 63, wave = tid >> 6;
  int wm = wave >> 1, wn = wave & 1;
  int l15 = lane & 15, l4 = lane >> 4;

  f32x4 acc[4][4];
#pragma unroll
  for (int i = 0; i < 4; ++i)
#pragma unroll
    for (int j = 0; j < 4; ++j) acc[i][j] = 0.f;

  int srow[4], scg[4];
#pragma unroll
  for (int i = 0; i < 4; ++i) {
    int ci = (wave + 4 * i) * 64 + lane;
    srow[i] = ci >> 3;                         // 8 chunks per 128B row
    scg[i] = (ci & 7) ^ (srow[i] & 7);         // pre-swizzled source chunk
  }

  int nk = K / BK;
  for (int kt = 0; kt < nk; ++kt) {
    __syncthreads();
#pragma unroll
    for (int i = 0; i < 4; ++i) {
      int gr = m0 + srow[i]; gr = gr < M ? gr : M - 1;
      size_t ga;
      if (ACM) {
        int ch = kt * BK + scg[i] * 8;
        ga = ((size_t)(ch >> 5) * M + gr) * 32 + (ch & 31);
      } else {
        ga = (size_t)gr * K + kt * BK + scg[i] * 8;
      }
      gld_lds16(Au + ga, As + (wave + 4 * i) * 512);
    }
#pragma unroll
    for (int i = 0; i < 4; ++i) {
      int gn = n0 + srow[i];
      gld_lds16(Bt + (size_t)gn * K + kt * BK + scg[i] * 8, Bs + (wave + 4 * i) * 512);
    }
    __syncthreads();

#pragma unroll
    for (int ks = 0; ks < 2; ++ks) {
      s16x8 af[4], bf[4];
#pragma unroll
      for (int f = 0; f < 4; ++f) {
        int r = wm * 64 + f * 16 + l15;
        int ca = (ks * 4 + l4) ^ (r & 7);
        af[f] = *(const s16x8*)(As + r * 64 + ca * 8);
        int nloc = wn * 64 + f * 16 + l15;
        int cb = (ks * 4 + l4) ^ (nloc & 7);
        bf[f] = *(const s16x8*)(Bs + nloc * 64 + cb * 8);
      }
#pragma unroll
      for (int fm = 0; fm < 4; ++fm)
#pragma unroll
        for (int fn = 0; fn < 4; ++fn)
          acc[fm][fn] = __builtin_amdgcn_mfma_f32_16x16x32_bf16(af[fm], bf[fn], acc[fm][fn], 0, 0, 0);
    }
  }

#pragma unroll
  for (int fm = 0; fm < 4; ++fm) {
#pragma unroll
    for (int fn = 0; fn < 4; ++fn) {
#pragma unroll
      for (int r = 0; r < 4; ++r) {
        int row = m0 + wm * 64 + fm * 16 + l4 * 4 + r;
        int col = n0 + wn * 64 + fn * 16 + l15;
        if (row < M && col < N) {
          if (OUTMODE == 1)
            ((float*)Coutv)[(size_t)row * N + col] = acc[fm][fn][r] + bias[col];
          else
            ((unsigned short*)Coutv)[((size_t)(col >> 5) * M + row) * 32 + (col & 31)]
                = f2bf(acc[fm][fn][r]);
        }
      }
    }
  }
}

// ------- GEMM layer1: A fp32 row-major via global_load_lds, cvt at frag read; OUT chunk-major -------
__global__ __launch_bounds__(256, 3) void k_gemmF(
    const float* __restrict__ Af, const unsigned short* __restrict__ Bt,
    unsigned short* __restrict__ Cout, int M, int N, int K, int MT, int NT)
{
  __shared__ __align__(16) float As[BM * BK];           // 32 KB fp32
  __shared__ __align__(16) unsigned short Bs[BN * BK];  // 16 KB

  int d = blockIdx.x;
  int xc = d & 7, sb = d >> 3;
  int nt = sb % NT, mt = (sb / NT) * 8 + xc;
  if (mt >= MT) return;
  int m0 = mt * BM, n0 = nt * BN;

  int tid = threadIdx.x, lane = tid & 63, wave = tid >> 6;
  int wm = wave >> 1, wn = wave & 1;
  int l15 = lane & 15, l4 = lane >> 4;

  f32x4 acc[4][4];
#pragma unroll
  for (int i = 0; i < 4; ++i)
#pragma unroll
    for (int j = 0; j < 4; ++j) acc[i][j] = 0.f;

  int arow[8], acs[8];
#pragma unroll
  for (int i = 0; i < 8; ++i) {
    int ci = (i * 4 + wave) * 64 + lane;
    arow[i] = ci >> 4;
    acs[i] = (ci & 15) ^ ((arow[i] & 7) << 1);  // pre-swizzled source chunk (pair-preserving)
  }
  int brow[4], bcg[4];
#pragma unroll
  for (int i = 0; i < 4; ++i) {
    int ci = (i * 4 + wave) * 64 + lane;
    brow[i] = ci >> 3;
    bcg[i] = (ci & 7) ^ (brow[i] & 7);
  }

  int nk = K / BK;
  for (int kt = 0; kt < nk; ++kt) {
    __syncthreads();
#pragma unroll
    for (int i = 0; i < 8; ++i) {
      int gr = m0 + arow[i]; gr = gr < M ? gr : M - 1;
      gld_lds16(Af + (size_t)gr * K + kt * BK + acs[i] * 4, As + (i * 4 + wave) * 256);
    }
#pragma unroll
    for (int i = 0; i < 4; ++i) {
      int gn = n0 + brow[i];
      gld_lds16(Bt + (size_t)gn * K + kt * BK + bcg[i] * 8, Bs + (i * 4 + wave) * 512);
    }
    __syncthreads();

#pragma unroll
    for (int ks = 0; ks < 2; ++ks) {
      s16x8 af[4], bf[4];
#pragma unroll
      for (int f = 0; f < 4; ++f) {
        int r = wm * 64 + f * 16 + l15;
        int c0 = (2 * (ks * 4 + l4)) ^ ((r & 7) << 1);
        f32x4 a0 = *(const f32x4*)(As + r * 64 + c0 * 4);
        f32x4 a1 = *(const f32x4*)(As + r * 64 + c0 * 4 + 4);
        s16x8 pk;
        pk[0] = (short)f2bf(a0[0]); pk[1] = (short)f2bf(a0[1]);
        pk[2] = (short)f2bf(a0[2]); pk[3] = (short)f2bf(a0[3]);
        pk[4] = (short)f2bf(a1[0]); pk[5] = (short)f2bf(a1[1]);
        pk[6] = (short)f2bf(a1[2]); pk[7] = (short)f2bf(a1[3]);
        af[f] = pk;
        int nloc = wn * 64 + f * 16 + l15;
        int cb = (ks * 4 + l4) ^ (nloc & 7);
        bf[f] = *(const s16x8*)(Bs + nloc * 64 + cb * 8);
      }
#pragma unroll
      for (int fm = 0; fm < 4; ++fm)
#pragma unroll
        for (int fn = 0; fn < 4; ++fn)
          acc[fm][fn] = __builtin_amdgcn_mfma_f32_16x16x32_bf16(af[fm], bf[fn], acc[fm][fn], 0, 0, 0);
    }
  }

#pragma unroll
  for (int fm = 0; fm < 4; ++fm) {
#pragma unroll
    for (int fn = 0; fn < 4; ++fn) {
#pragma unroll
      for (int r = 0; r < 4; ++r) {
        int row = m0 + wm * 64 + fm * 16 + l4 * 4 + r;
        int col = n0 + wn * 64 + fn * 16 + l15;
        if (row < M && col < N)
          Cout[((size_t)(col >> 5) * M + row) * 32 + (col & 31)] = f2bf(acc[fm][fn][r]);
      }
    }
  }
}

// -------- channel-chunked aggregation: one 32-ch chunk per launch (L2-resident, 3.2 MB) --------
// wave = 1 dst node; lane = (edge-slot 0..3) x (ch-pair 0..15); depth-8 pipeline; no shfl broadcasts.
template<int BNRELU, int BIAS>
__global__ __launch_bounds__(256) void k_aggc(
    const unsigned short* __restrict__ hc, const unsigned* __restrict__ ewp,
    const unsigned* __restrict__ offs,
    const float* __restrict__ bias, const float* __restrict__ gam,
    const float* __restrict__ bet, const float* __restrict__ mea,
    const float* __restrict__ var,
    unsigned* __restrict__ outp, int nN, int cb)
{
  int wave = threadIdx.x >> 6, lane = threadIdx.x & 63;
  int v = blockIdx.x * 4 + wave;
  if (v >= nN) return;
  unsigned beg = offs[v];
  int len = (int)(offs[v + 1] - beg);
  int eslot = lane >> 4, cp = lane & 15;
  const unsigned* hp = (const unsigned*)hc;
  float a0 = 0.f, a1 = 0.f;
  int ngrp = (len + 31) >> 5;

  unsigned q[8]; float w[8];
#pragma unroll
  for (int r = 0; r < 8; ++r) {
    int er = r * 4 + eslot;
    unsigned pck = 0;
    if (er < len) pck = __builtin_nontemporal_load(&ewp[beg + er]);
    w[r] = bf2f((unsigned short)(pck & 0xffffu));
    q[r] = hp[(size_t)(pck >> 16) * 16 + cp];
  }
  for (int g = 1; g < ngrp; ++g) {
    unsigned q2[8]; float w2[8];
#pragma unroll
    for (int r = 0; r < 8; ++r) {
      int er = g * 32 + r * 4 + eslot;
      unsigned pck = 0;
      if (er < len) pck = __builtin_nontemporal_load(&ewp[beg + er]);
      w2[r] = bf2f((unsigned short)(pck & 0xffffu));
      q2[r] = hp[(size_t)(pck >> 16) * 16 + cp];
    }
#pragma unroll
    for (int r = 0; r < 8; ++r) {
      float lo = __uint_as_float(q[r] << 16);
      float hi = __uint_as_float(q[r] & 0xffff0000u);
      a0 += lo * w[r]; a1 += hi * w[r];
    }
#pragma unroll
    for (int r = 0; r < 8; ++r) { q[r] = q2[r]; w[r] = w2[r]; }
  }
#pragma unroll
  for (int r = 0; r < 8; ++r) {
    float lo = __uint_as_float(q[r] << 16);
    float hi = __uint_as_float(q[r] & 0xffff0000u);
    a0 += lo * w[r]; a1 += hi * w[r];
  }

  a0 += __shfl_xor(a0, 16); a0 += __shfl_xor(a0, 32);
  a1 += __shfl_xor(a1, 16); a1 += __shfl_xor(a1, 32);

  if (lane < 16) {
    int ch0 = cb + cp * 2, ch1 = ch0 + 1;
    float v0 = a0, v1 = a1;
    if (BIAS) { v0 += bias[ch0]; v1 += bias[ch1]; }
    if (BNRELU) {
      v0 = (v0 - mea[ch0]) * rsqrtf(var[ch0] + EPSBN) * gam[ch0] + bet[ch0];
      v1 = (v1 - mea[ch1]) * rsqrtf(var[ch1] + EPSBN) * gam[ch1] + bet[ch1];
      v0 = fmaxf(v0, 0.f); v1 = fmaxf(v1, 0.f);
    }
    unsigned u = (unsigned)f2bf(v0) | ((unsigned)f2bf(v1) << 16);
    __builtin_nontemporal_store(u, &outp[(size_t)v * 16 + cp]);
  }
}

// ---------------- launch ----------------
extern "C" void kernel_launch(void* const* d_in, const int* in_sizes, int n_in,
                              void* d_out, int out_size, void* d_ws, size_t ws_size,
                              hipStream_t stream) {
  const float* x   = (const float*)d_in[0];
  const int*   ei  = (const int*)d_in[1];
  const float* W1  = (const float*)d_in[2];
  const float* b1  = (const float*)d_in[3];
  const float* g1  = (const float*)d_in[4];
  const float* be1 = (const float*)d_in[5];
  const float* m1  = (const float*)d_in[6];
  const float* v1  = (const float*)d_in[7];
  const float* W2  = (const float*)d_in[8];
  const float* b2  = (const float*)d_in[9];
  const float* g2  = (const float*)d_in[10];
  const float* be2 = (const float*)d_in[11];
  const float* m2  = (const float*)d_in[12];
  const float* v2  = (const float*)d_in[13];
  const float* W3  = (const float*)d_in[14];
  const float* b3  = (const float*)d_in[15];

  const int IN = 1280, H = 256, OUT = 500, OUTP = 512;
  int E  = in_sizes[1] / 2;
  int nN = in_sizes[0] / IN;
  const int* srcI = ei;
  const int* dstI = ei + E;

  char* p = (char*)d_ws;
  auto carve = [&](size_t bytes) { char* r = p; p += (bytes + 511) & ~(size_t)511; return r; };
  unsigned short* Wt1 = (unsigned short*)carve((size_t)H * IN * 2);
  unsigned short* Wt2 = (unsigned short*)carve((size_t)H * H * 2);
  unsigned short* Wt3 = (unsigned short*)carve((size_t)OUTP * H * 2);
  unsigned* deg  = (unsigned*)carve((size_t)nN * 4);
  float*    dinv = (float*)carve((size_t)nN * 4);
  unsigned* offs = (unsigned*)carve((size_t)(nN + 1) * 4);
  unsigned* cur  = (unsigned*)carve((size_t)nN * 4);
  unsigned* bsum = (unsigned*)carve(256 * 4);
  unsigned* bpre = (unsigned*)carve(256 * 4);
  unsigned* ewp  = (unsigned*)carve((size_t)(E + nN) * 4);
  unsigned short* bufA = (unsigned short*)carve((size_t)nN * H * 2);  // chunk-major [8][nN][32]
  unsigned short* bufB = (unsigned short*)carve((size_t)nN * H * 2);  // chunk-major [8][nN][32]

  int NB = (nN + 255) / 256;
  k_init_deg<<<NB, 256, 0, stream>>>(deg, nN);
  k_count<<<(E + 255) / 256, 256, 0, stream>>>(dstI, deg, E);
  k_prep2<<<NB, 256, 0, stream>>>(deg, dinv, bsum, nN);
  k_scan_top<<<1, 256, 0, stream>>>(bsum, bpre, NB, offs, nN);
  k_scan_fin<<<NB, 256, 0, stream>>>(deg, bpre, offs, cur, nN);
  k_fillw<<<(E + nN + 255) / 256, 256, 0, stream>>>(srcI, dstI, dinv, cur, ewp, E, nN);
  k_wt3<<<(H * IN + H * H + OUTP * H + 255) / 256, 256, 0, stream>>>(W1, Wt1, W2, Wt2, W3, Wt3);

  int MT = (nN + BM - 1) / BM;          // 391
  int mg = (MT + 7) / 8;                // 49
  int nAgg = (nN + 3) / 4;

  // layer 1:  h1 = x*W1 (chunk-major) ; act1 = BNReLU(agg(h1)+b1) per chunk
  k_gemmF<<<mg * 8 * 2, 256, 0, stream>>>(x, Wt1, bufA, nN, H, IN, MT, 2);
  for (int c = 0; c < 8; ++c)
    k_aggc<1, 1><<<nAgg, 256, 0, stream>>>(bufA + (size_t)c * nN * 32, ewp, offs,
                                           b1, g1, be1, m1, v1,
                                           (unsigned*)bufB + (size_t)c * nN * 16, nN, c * 32);
  // layer 2:  h2 = act1*W2 ; act2 = BNReLU(agg(h2)+b2)
  k_gemm<0, 1><<<mg * 8 * 2, 256, 0, stream>>>(bufB, Wt2, bufA, nullptr, nN, H, H, MT, 2);
  for (int c = 0; c < 8; ++c)
    k_aggc<1, 1><<<nAgg, 256, 0, stream>>>(bufA + (size_t)c * nN * 32, ewp, offs,
                                           b2, g2, be2, m2, v2,
                                           (unsigned*)bufB + (size_t)c * nN * 16, nN, c * 32);
  // layer 3 (reordered):  out = (agg(act2)) * W3 + b3
  for (int c = 0; c < 8; ++c)
    k_aggc<0, 0><<<nAgg, 256, 0, stream>>>(bufB + (size_t)c * nN * 32, ewp, offs,
                                           nullptr, nullptr, nullptr, nullptr, nullptr,
                                           (unsigned*)bufA + (size_t)c * nN * 16, nN, c * 32);
  k_gemm<1, 1><<<mg * 8 * 4, 256, 0, stream>>>(bufA, Wt3, d_out, b3, nN, OUT, H, MT, 4);
}